// Round 14
// baseline (1059.397 us; speedup 1.0000x reference)
//
#include <hip/hip_runtime.h>
#include <hip/hip_bf16.h>
#include <math.h>

typedef __attribute__((ext_vector_type(8))) short bf16x8;
typedef __attribute__((ext_vector_type(4))) float f32x4;
typedef unsigned short u16;
typedef unsigned int u32;
typedef unsigned long long u64;

#define NN 370
#define HH 64
#define LL 8
#define TT 64
#define BTOT 512            // B*T
#define RR (BTOT*NN)        // 189440 rows
#define KTOPK 37
#define SPLITK 37

// ---------- helpers ----------
__device__ inline u16 f2bf(float f){
  __hip_bfloat16 h = __float2bfloat16(f);
  return __builtin_bit_cast(u16, h);
}
__device__ inline float bf2f(short s){
  u32 v = ((u32)(u16)s) << 16;
  return __builtin_bit_cast(float, v);
}
__device__ inline float gelu_f(float x){ return 0.5f * x * (1.0f + erff(x * 0.70710678118654752440f)); }

// swizzled LDS store/load of 16B (8 bf16). stride must be a multiple of 128 bytes.
__device__ inline void sts16(char* lds, int row, int kb, int stride, bf16x8 v){
  *reinterpret_cast<bf16x8*>(lds + row*stride + (kb ^ ((row&7)<<4))) = v;
}
__device__ inline bf16x8 lds16(const char* lds, int row, int kb, int stride){
  return *reinterpret_cast<const bf16x8*>(lds + row*stride + (kb ^ ((row&7)<<4)));
}
// direct-global fragment load from pre-swizzled Bt[col][k] tile
__device__ inline bf16x8 gldB(const char* Bt, int c, int kb, int stride){
  return *reinterpret_cast<const bf16x8*>(Bt + c*stride + (kb ^ ((c&7)<<4)));
}

// ---------- prep kernels ----------
__global__ void kzero(float* __restrict__ p, size_t n){
  for(size_t i = (size_t)blockIdx.x*256 + threadIdx.x; i < n; i += (size_t)gridDim.x*256) p[i] = 0.f;
}

__global__ void kbuildA(const int* __restrict__ ei, const float* __restrict__ ew, float* __restrict__ Araw, int E){
  int e = blockIdx.x*256 + threadIdx.x;
  if(e < E){
    int src = ei[e], dst = ei[E + e];
    atomicAdd(&Araw[dst*NN + src], ew[e]);
  }
}

// parallel gcn-norm for fixed A: one block (64 lanes) per row
__global__ __launch_bounds__(64) void knormF(float* __restrict__ Araw, float* __restrict__ dinvF){
  int i = blockIdx.x, ln = threadIdx.x;
  float d0 = Araw[i*NN + i];
  float s = 0.f;
  for(int j = ln; j < NN; j += 64) s += Araw[i*NN + j];
#pragma unroll
  for(int o=1;o<64;o<<=1) s += __shfl_xor(s, o, 64);
  if(ln == 0){
    if(d0 == 0.f){ Araw[i*NN+i] = 1.f; s += 1.f; }
    dinvF[i] = rsqrtf(s);
  }
}

// adaptive adjacency: one block per (row i, layer l).
// Exact jax top_k via bitonic sort of packed (value,index) keys.
__global__ __launch_bounds__(512) void kadapt(const float* __restrict__ esrc, const float* __restrict__ etgt,
                                              float* __restrict__ ArawA, float* __restrict__ dinvA){
  __shared__ float tgT[16][372];
  __shared__ float red[8];
  __shared__ u64 keys[512];
  __shared__ int diagflag;
  int i = blockIdx.x, l = blockIdx.y, tid = threadIdx.x;
  const float* Et = etgt + (size_t)l*NN*16;
  for(int idx = tid; idx < NN*16; idx += 512)
    tgT[idx & 15][idx >> 4] = Et[idx];
  float sr[16];
  const float* Es = esrc + ((size_t)l*NN + i)*16;
#pragma unroll
  for(int k=0;k<16;k++) sr[k] = Es[k];
  if(tid == 0) diagflag = 0;
  __syncthreads();
  bool act = tid < NN;
  float s = 0.f;
  if(act){
    float d = 0.f;
#pragma unroll
    for(int k=0;k<16;k++) d += sr[k]*tgT[k][tid];
    s = fmaxf(d, 0.f);
  }
  float v = act ? s : -1.f;
#pragma unroll
  for(int o=1;o<64;o<<=1) v = fmaxf(v, __shfl_xor(v,o,64));
  if((tid&63)==0) red[tid>>6] = v;
  __syncthreads();
  float mx = red[0];
#pragma unroll
  for(int q=1;q<8;q++) mx = fmaxf(mx, red[q]);
  __syncthreads();
  float e = act ? expf(s - mx) : 0.f;
  float t = e;
#pragma unroll
  for(int o=1;o<64;o<<=1) t += __shfl_xor(t,o,64);
  if((tid&63)==0) red[tid>>6] = t;
  __syncthreads();
  float sum = 0.f;
#pragma unroll
  for(int q=0;q<8;q++) sum += red[q];
  float p = e / sum;
  u32 fb = __builtin_bit_cast(u32, p);
  keys[tid] = act ? ((((u64)fb)<<32) | (u64)(0xFFFFFFFFu - (u32)tid)) : 0ULL;
  __syncthreads();
  for(int k2=2; k2<=512; k2<<=1){
    for(int j=k2>>1; j>0; j>>=1){
      int ixj = tid ^ j;
      if(ixj > tid){
        u64 a = keys[tid], b = keys[ixj];
        bool dirUp = ((tid & k2) == 0);
        if(dirUp ? (a < b) : (a > b)){ keys[tid] = b; keys[ixj] = a; }
      }
      __syncthreads();
    }
  }
  float myval = 0.f; int myidx = -1;
  if(tid < KTOPK){
    u64 kk = keys[tid];
    myidx = (int)(0xFFFFFFFFu - (u32)kk);
    myval = __builtin_bit_cast(float, (u32)(kk>>32));
    if(myidx == i) diagflag = 1;
  }
  __syncthreads();
  float dsum = (tid < KTOPK) ? myval : 0.f;
  if(tid < 64){
#pragma unroll
    for(int o=1;o<64;o<<=1) dsum += __shfl_xor(dsum,o,64);
    if(tid == 0) dinvA[l*NN + i] = rsqrtf(dsum + (diagflag ? 0.f : 1.f));
  }
  if(tid < KTOPK) ArawA[((size_t)l*NN + i)*NN + myidx] = myval;
  if(tid == 0 && !diagflag) ArawA[((size_t)l*NN + i)*NN + i] = 1.f;
}

// build normalized dense bf16 A_cat[l] = [A_fixed(384) | A_adapt(384)] over k=768
__global__ void kacat(const float* __restrict__ Araw, const float* __restrict__ ArawA,
                      const float* __restrict__ dinvF, const float* __restrict__ dinvA,
                      u16* __restrict__ Acat){
  int idx = blockIdx.x*256 + threadIdx.x;
  if(idx >= LL*384*768) return;
  int k = idx % 768; int m = (idx / 768) % 384; int l = idx / (768*384);
  float v = 0.f;
  if(m < NN){
    if(k < 384){
      if(k < NN) v = dinvF[m]*Araw[m*NN+k]*dinvF[k];
    } else {
      int n = k - 384;
      if(n < NN) v = dinvA[l*NN+m]*ArawA[((size_t)l*NN+m)*NN+n]*dinvA[l*NN+n];
    }
  }
  Acat[idx] = f2bf(v);
}

// pre-transposed + pre-swizzled weight tiles Bt[col][k]
__global__ void kbt_small(const float* __restrict__ inW, const float* __restrict__ e1W, const float* __restrict__ e2W,
                          u16* __restrict__ BtIN, u16* __restrict__ BtE1, u16* __restrict__ BtE2){
  const float* W = blockIdx.x==0 ? inW : (blockIdx.x==1 ? e1W : e2W);
  u16* Bt = blockIdx.x==0 ? BtIN : (blockIdx.x==1 ? BtE1 : BtE2);
  for(int idx = threadIdx.x; idx < 4096; idx += 256){
    int c = idx >> 6, k = idx & 63;
    *(u16*)((char*)Bt + c*128 + ((k*2) ^ ((c&7)<<4))) = f2bf(W[k*64 + c]);
  }
}

__global__ void kbt_layer(const float* __restrict__ gcnfW, const float* __restrict__ gcnaW,
                          const float* __restrict__ filtW, const float* __restrict__ gateW,
                          const float* __restrict__ skipW, const float* __restrict__ resW,
                          u16* __restrict__ BtUV, u16* __restrict__ BtCV, u16* __restrict__ BtSR){
  int l = blockIdx.x, which = blockIdx.y;
  if(which == 0){            // [Wf | Wa] : 128 cols x 64 k
    u16* Bt = BtUV + (size_t)l*128*64;
    for(int idx=threadIdx.x; idx<8192; idx+=256){
      int c = idx>>6, k = idx&63;
      float v = (c<64) ? gcnfW[(size_t)l*4096 + k*64 + c] : gcnaW[(size_t)l*4096 + k*64 + (c-64)];
      *(u16*)((char*)Bt + c*128 + ((k*2) ^ ((c&7)<<4))) = f2bf(v);
    }
  } else if(which == 1){     // conv [filt | gate] : 128 cols x 128 k
    u16* Bt = BtCV + (size_t)l*128*128;
    for(int idx=threadIdx.x; idx<16384; idx+=256){
      int c = idx>>7, k = idx&127;
      const float* W = (c<64) ? filtW : gateW;
      int o = c & 63, ii = k & 63, tap = (k<64) ? 1 : 0;
      float v = W[(size_t)l*8192 + o*128 + ii*2 + tap];
      *(u16*)((char*)Bt + c*256 + ((k*2) ^ ((c&7)<<4))) = f2bf(v);
    }
  } else {                   // [skip | res] : 128 cols x 64 k
    u16* Bt = BtSR + (size_t)l*128*64;
    for(int idx=threadIdx.x; idx<8192; idx+=256){
      int c = idx>>6, k = idx&63;
      float v = (c<64) ? skipW[(size_t)l*4096 + c*64 + k] : resW[(size_t)l*4096 + (c-64)*64 + k];
      *(u16*)((char*)Bt + c*128 + ((k*2) ^ ((c&7)<<4))) = f2bf(v);
    }
  }
}

// eeg1_W (23680x256 fp32) -> Wt (256 x 23680 bf16)
__global__ void ktrans(const float* __restrict__ W, u16* __restrict__ Wt){
  __shared__ float tile[64][65];
  int kb = blockIdx.x*64, cb = blockIdx.y*64;
  for(int idx = threadIdx.x; idx < 4096; idx += 256){
    int kk = idx>>6, cc = idx&63;
    tile[kk][cc] = W[(size_t)(kb+kk)*256 + cb+cc];
  }
  __syncthreads();
  for(int idx = threadIdx.x; idx < 4096; idx += 256){
    int cc = idx>>6, kk = idx&63;
    Wt[(size_t)(cb+cc)*23680 + kb+kk] = f2bf(tile[kk][cc]);
  }
}

// ---------- main pipeline kernels ----------
// input proj: x = X@inW+b -> xbf (bf16). LDS-free: A fragments converted in-reg.
__global__ __launch_bounds__(256) void krowmm_in(const float* __restrict__ X, const u16* __restrict__ Bt,
                                                 const float* __restrict__ bias,
                                                 u16* __restrict__ xbf){
  int tid = threadIdx.x;
  int w = tid>>6, ln = tid&63, lr = ln&15, hi = ln>>4;
  int kboff = hi<<4;
  size_t r = (size_t)blockIdx.x*64 + w*16 + lr;
  f32x4 acc[4];
#pragma unroll
  for(int i=0;i<4;i++) acc[i] = f32x4{0.f,0.f,0.f,0.f};
  const char* BI = (const char*)Bt;
#pragma unroll
  for(int kt=0; kt<2; ++kt){
    const float* xr = X + r*64 + kt*32 + hi*8;
    float4 pa = ((const float4*)xr)[0], pb = ((const float4*)xr)[1];
    bf16x8 a;
    a[0]=(short)f2bf(pa.x); a[1]=(short)f2bf(pa.y); a[2]=(short)f2bf(pa.z); a[3]=(short)f2bf(pa.w);
    a[4]=(short)f2bf(pb.x); a[5]=(short)f2bf(pb.y); a[6]=(short)f2bf(pb.z); a[7]=(short)f2bf(pb.w);
#pragma unroll
    for(int nt=0; nt<4; ++nt){
      bf16x8 b = gldB(BI, nt*16 + lr, kt*64 + kboff, 128);
      acc[nt] = __builtin_amdgcn_mfma_f32_16x16x32_bf16(a, b, acc[nt], 0, 0, 0);
    }
  }
  size_t r0 = (size_t)blockIdx.x*64;
#pragma unroll
  for(int nt=0; nt<4; ++nt){
    int c = nt*16 + lr;
    float bv = bias[c];
#pragma unroll
    for(int rr=0;rr<4;++rr){
      int row = w*16 + hi*4 + rr;
      xbf[(r0+row)*64 + c] = f2bf(acc[nt][rr] + bv);
    }
  }
}

// per-(b,t): UV^T computed in-kernel from xbf, then OUT = A_cat @ [U;V] + biases.
// M-SPLIT: grid (2, BTOT), 256 threads (4 waves). Each block computes 192 output
// rows but the full 384-node UV tile (duplicated across the 2 halves -> UV work
// per wave doubles; UV is 14% of FLOPs). 48KB LDS -> 3 blocks/CU (was grid-capped at 2).
__global__ __launch_bounds__(256) void kgcn(const u16* __restrict__ xbf, const u16* __restrict__ BtUV,
                                            const u16* __restrict__ Acat,
                                            const float* __restrict__ bfb, const float* __restrict__ bab,
                                            u16* __restrict__ t2){
  __shared__ char uvt[64*768];   // 48KB: one phase of UV^T [h=64][node 384]
  int mhalf = blockIdx.x, bt = blockIdx.y, tid = threadIdx.x;
  int w = tid>>6, ln = tid&63, lr = ln&15, hi = ln>>4;
  int kboff = hi<<4;
  f32x4 acc[12];
#pragma unroll
  for(int j=0;j<12;j++) acc[j] = f32x4{0.f,0.f,0.f,0.f};
  const char* xb = (const char*)(xbf + (size_t)bt*NN*64);
  for(int p=0; p<2; ++p){
    // --- UV phase p: 6 node-tiles per wave, store-after-compute ---
    bf16x8 bw[2][4];
#pragma unroll
    for(int kt=0;kt<2;++kt)
#pragma unroll
      for(int nt=0;nt<4;++nt){
        int c = p*64 + nt*16 + lr;
        bw[kt][nt] = *reinterpret_cast<const bf16x8*>((const char*)BtUV + c*128 + ((kt*64 + kboff) ^ ((c&7)<<4)));
      }
    __syncthreads();   // previous phase's A-loop readers done
#pragma unroll
    for(int j6=0;j6<6;++j6){
      int tile = w*6 + j6;             // 0..23 node-tile
      int node = tile*16 + lr;
      bf16x8 a0, a1;
      if(node < NN){
        a0 = *reinterpret_cast<const bf16x8*>(xb + (size_t)node*128 + kboff);
        a1 = *reinterpret_cast<const bf16x8*>(xb + (size_t)node*128 + 64 + kboff);
      } else {
        bf16x8 z = {0,0,0,0,0,0,0,0}; a0 = z; a1 = z;
      }
      f32x4 uv[4];
#pragma unroll
      for(int nt=0;nt<4;++nt) uv[nt] = f32x4{0.f,0.f,0.f,0.f};
#pragma unroll
      for(int nt=0;nt<4;++nt){
        uv[nt] = __builtin_amdgcn_mfma_f32_16x16x32_bf16(a0, bw[0][nt], uv[nt], 0,0,0);
        uv[nt] = __builtin_amdgcn_mfma_f32_16x16x32_bf16(a1, bw[1][nt], uv[nt], 0,0,0);
      }
      int nd = tile*16 + hi*4;
#pragma unroll
      for(int nt=0;nt<4;++nt){
        int cl = nt*16 + lr;
        u64 pk = (u64)((u32)f2bf(uv[nt][0]) | ((u32)f2bf(uv[nt][1])<<16))
               | ((u64)((u32)f2bf(uv[nt][2]) | ((u32)f2bf(uv[nt][3])<<16)) << 32);
        *(u64*)(uvt + cl*768 + ((nd*2) ^ ((cl&7)<<4))) = pk;
      }
    }
    __syncthreads();
    // --- A-loop phase p: 3 M-tiles per wave (rows mhalf*192 + w*48 ..) ---
    int mb = mhalf*12 + w*3;
    const char* abase = (const char*)Acat + p*768 + kboff;
    __builtin_amdgcn_s_setprio(1);
#pragma unroll
    for(int kt=0; kt<12; ++kt){
      bf16x8 a0 = *reinterpret_cast<const bf16x8*>(abase + (size_t)((mb+0)*16 + lr)*1536 + kt*64);
      bf16x8 a1 = *reinterpret_cast<const bf16x8*>(abase + (size_t)((mb+1)*16 + lr)*1536 + kt*64);
      bf16x8 a2 = *reinterpret_cast<const bf16x8*>(abase + (size_t)((mb+2)*16 + lr)*1536 + kt*64);
      bf16x8 b0 = lds16(uvt, 0*16 + lr, kt*64 + kboff, 768);
      bf16x8 b1 = lds16(uvt, 1*16 + lr, kt*64 + kboff, 768);
      bf16x8 b2 = lds16(uvt, 2*16 + lr, kt*64 + kboff, 768);
      bf16x8 b3 = lds16(uvt, 3*16 + lr, kt*64 + kboff, 768);
      acc[0]  = __builtin_amdgcn_mfma_f32_16x16x32_bf16(a0, b0, acc[0],  0,0,0);
      acc[1]  = __builtin_amdgcn_mfma_f32_16x16x32_bf16(a0, b1, acc[1],  0,0,0);
      acc[2]  = __builtin_amdgcn_mfma_f32_16x16x32_bf16(a0, b2, acc[2],  0,0,0);
      acc[3]  = __builtin_amdgcn_mfma_f32_16x16x32_bf16(a0, b3, acc[3],  0,0,0);
      acc[4]  = __builtin_amdgcn_mfma_f32_16x16x32_bf16(a1, b0, acc[4],  0,0,0);
      acc[5]  = __builtin_amdgcn_mfma_f32_16x16x32_bf16(a1, b1, acc[5],  0,0,0);
      acc[6]  = __builtin_amdgcn_mfma_f32_16x16x32_bf16(a1, b2, acc[6],  0,0,0);
      acc[7]  = __builtin_amdgcn_mfma_f32_16x16x32_bf16(a1, b3, acc[7],  0,0,0);
      acc[8]  = __builtin_amdgcn_mfma_f32_16x16x32_bf16(a2, b0, acc[8],  0,0,0);
      acc[9]  = __builtin_amdgcn_mfma_f32_16x16x32_bf16(a2, b1, acc[9],  0,0,0);
      acc[10] = __builtin_amdgcn_mfma_f32_16x16x32_bf16(a2, b2, acc[10], 0,0,0);
      acc[11] = __builtin_amdgcn_mfma_f32_16x16x32_bf16(a2, b3, acc[11], 0,0,0);
    }
    __builtin_amdgcn_s_setprio(0);
  }
#pragma unroll
  for(int mi=0; mi<3; ++mi){
    int mt = mhalf*12 + w*3 + mi;
    int mbase = mt*16 + hi*4;
#pragma unroll
    for(int nt=0; nt<4; ++nt){
      int col = nt*16 + lr;
      float bias = bfb[col] + bab[col];
#pragma unroll
      for(int r=0;r<4;++r){
        int m = mbase + r;
        if(m < NN) t2[((size_t)bt*NN + m)*64 + col] = f2bf(acc[mi*4+nt][r] + bias);
      }
    }
  }
}

// fused: gated causal conv + skip/res 1x1 + residual + LayerNorm + skip accum.
// Conv A direct from global; B direct from L1/L2. Two DISJOINT LDS stages
// (act bf16 8KB @0, skip/res bf16 16KB @8KB) -> only 2 barriers, 24KB total.
__global__ __launch_bounds__(256) void kcsr(const u16* __restrict__ t2, const u16* __restrict__ BtC,
                                            const u16* __restrict__ BtS,
                                            const float* __restrict__ fb, const float* __restrict__ gb,
                                            const float* __restrict__ sb, const float* __restrict__ rb,
                                            const float* __restrict__ lng, const float* __restrict__ lnb,
                                            u16* __restrict__ skip,
                                            u16* __restrict__ xbf, int dil, int first, int douv){
  __shared__ char sA[24576];
  char* sact = sA;           // [64][128B] bf16 activation stage
  char* ssr  = sA + 8192;    // [64][256B] bf16 skip(0..63)/res(64..127) stage
  int blk = blockIdx.x, tid = threadIdx.x;
  int w = tid>>6, ln = tid&63, lr = ln&15, hi = ln>>4;
  int kboff = hi<<4;
  int r0 = blk*64;
  int r = r0 + w*16 + lr;                 // this thread's conv row
  int t = (r / NN) & (TT-1);              // time index of this row
  const char* cur = (const char*)t2 + (size_t)r*128;
  const char* prv = cur - (size_t)dil*NN*128;
  bf16x8 a0 = *reinterpret_cast<const bf16x8*>(cur + kboff);
  bf16x8 a1 = *reinterpret_cast<const bf16x8*>(cur + 64 + kboff);
  bf16x8 a2, a3;
  if(t >= dil){
    a2 = *reinterpret_cast<const bf16x8*>(prv + kboff);
    a3 = *reinterpret_cast<const bf16x8*>(prv + 64 + kboff);
  } else {
    bf16x8 z = {0,0,0,0,0,0,0,0}; a2 = z; a3 = z;
  }
  const char* BC = (const char*)BtC;
  f32x4 acc[8];
#pragma unroll
  for(int i=0;i<8;i++) acc[i] = f32x4{0.f,0.f,0.f,0.f};
  bf16x8 afr[4] = {a0, a1, a2, a3};
#pragma unroll
  for(int kt=0; kt<4; ++kt){
    bf16x8 bfr[8];
#pragma unroll
    for(int nt=0; nt<8; ++nt)
      bfr[nt] = gldB(BC, nt*16 + lr, kt*64 + kboff, 256);
#pragma unroll
    for(int nt=0; nt<8; ++nt)
      acc[nt] = __builtin_amdgcn_mfma_f32_16x16x32_bf16(afr[kt], bfr[nt], acc[nt], 0, 0, 0);
  }
  u16 qv[4][4];
#pragma unroll
  for(int nt=0; nt<4; ++nt){
    int o = nt*16 + lr;
    float fbv = fb[o], gbv = gb[o];
#pragma unroll
    for(int rr=0;rr<4;++rr){
      float fv = acc[nt][rr] + fbv;
      float gv = acc[nt+4][rr] + gbv;
      float ef = __expf(-2.f*fv);
      float th = (1.f - ef) * __builtin_amdgcn_rcpf(1.f + ef);
      float sg = __builtin_amdgcn_rcpf(1.f + __expf(-gv));
      qv[nt][rr] = f2bf(th * sg);
    }
  }
#pragma unroll
  for(int nt=0; nt<4; ++nt){
    int col = nt*16 + lr;
#pragma unroll
    for(int rr=0;rr<4;++rr){
      int row = w*16 + hi*4 + rr;
      *(u16*)(sact + row*128 + ((col*2) ^ ((row&7)<<4))) = qv[nt][rr];
    }
  }
  __syncthreads();
  const char* BS = (const char*)BtS;
  f32x4 as[8];
#pragma unroll
  for(int i=0;i<8;i++) as[i] = f32x4{0.f,0.f,0.f,0.f};
#pragma unroll
  for(int kt=0; kt<2; ++kt){
    bf16x8 a = lds16(sact, w*16 + lr, kt*64 + kboff, 128);
    bf16x8 bfr[8];
#pragma unroll
    for(int nt=0; nt<8; ++nt)
      bfr[nt] = gldB(BS, nt*16 + lr, kt*64 + kboff, 128);
#pragma unroll
    for(int nt=0; nt<8; ++nt)
      as[nt] = __builtin_amdgcn_mfma_f32_16x16x32_bf16(a, bfr[nt], as[nt], 0, 0, 0);
  }
  // as[0..3] = skip cols (0..63), as[4..7] = res cols (0..63)
  // write to DISJOINT sr region (no barrier needed: act readers unaffected)
#pragma unroll
  for(int nt=0; nt<4; ++nt){
    int c = nt*16 + lr;
#pragma unroll
    for(int rr=0;rr<4;++rr){
      int row = w*16 + hi*4 + rr;
      *(u16*)(ssr + row*256 + (((c)*2)      ^ ((row&7)<<4))) = f2bf(as[nt][rr]);
      *(u16*)(ssr + row*256 + (((64+c)*2)   ^ ((row&7)<<4))) = f2bf(as[4+nt][rr]);
    }
  }
  __syncthreads();
  // ---- row-major epilogue: thread = (row = tid>>2, 16-col segment = tid&3) ----
  int row = tid >> 2, seg = tid & 3;
  int c0 = seg * 16;
  bf16x8 vs0 = *reinterpret_cast<const bf16x8*>(ssr + row*256 + (((c0)*2)      ^ ((row&7)<<4)));
  bf16x8 vs1 = *reinterpret_cast<const bf16x8*>(ssr + row*256 + (((c0+8)*2)    ^ ((row&7)<<4)));
  bf16x8 vr0 = *reinterpret_cast<const bf16x8*>(ssr + row*256 + (((64+c0)*2)   ^ ((row&7)<<4)));
  bf16x8 vr1 = *reinterpret_cast<const bf16x8*>(ssr + row*256 + (((64+c0+8)*2) ^ ((row&7)<<4)));
  float sk[16], re[16];
#pragma unroll
  for(int i=0;i<8;++i){ sk[i] = bf2f(vs0[i]); sk[8+i] = bf2f(vs1[i]); }
#pragma unroll
  for(int i=0;i<8;++i){ re[i] = bf2f(vr0[i]); re[8+i] = bf2f(vr1[i]); }
  size_t gr = (size_t)(r0 + row)*64 + c0;
  bf16x8 xv0 = *reinterpret_cast<const bf16x8*>(xbf + gr);
  bf16x8 xv1 = *reinterpret_cast<const bf16x8*>(xbf + gr + 8);
  float y[16]; float s1 = 0.f, s2 = 0.f;
#pragma unroll
  for(int i=0;i<16;++i){
    float xo = bf2f(i < 8 ? xv0[i] : xv1[i-8]);
    float vv = re[i] + rb[c0+i] + xo;
    y[i] = vv; s1 += vv; s2 += vv*vv;
  }
  s1 += __shfl_xor(s1, 1, 64); s1 += __shfl_xor(s1, 2, 64);
  s2 += __shfl_xor(s2, 1, 64); s2 += __shfl_xor(s2, 2, 64);
  float m = s1 * (1.f/64.f);
  float var = s2 * (1.f/64.f) - m*m;
  float rstd = rsqrtf(var + 1e-5f);
  if(douv){
    bf16x8 o0, o1;
#pragma unroll
    for(int i=0;i<16;++i){
      float xo = (y[i] - m) * rstd * lng[c0+i] + lnb[c0+i];
      if(i < 8) o0[i] = (short)f2bf(xo); else o1[i-8] = (short)f2bf(xo);
    }
    *reinterpret_cast<bf16x8*>(xbf + gr) = o0;
    *reinterpret_cast<bf16x8*>(xbf + gr + 8) = o1;
  }
  bf16x8 so0, so1;
  if(first){
#pragma unroll
    for(int i=0;i<16;++i){
      float sv = sk[i] + sb[c0+i];
      if(i < 8) so0[i] = (short)f2bf(sv); else so1[i-8] = (short)f2bf(sv);
    }
  } else {
    bf16x8 sp0 = *reinterpret_cast<const bf16x8*>(skip + gr);
    bf16x8 sp1 = *reinterpret_cast<const bf16x8*>(skip + gr + 8);
#pragma unroll
    for(int i=0;i<16;++i){
      float old = bf2f(i < 8 ? sp0[i] : sp1[i-8]);
      float sv = old + sk[i] + sb[c0+i];
      if(i < 8) so0[i] = (short)f2bf(sv); else so1[i-8] = (short)f2bf(sv);
    }
  }
  *reinterpret_cast<bf16x8*>(skip + gr) = so0;
  *reinterpret_cast<bf16x8*>(skip + gr + 8) = so1;
}

// fused end convs: h2 = gelu(gelu(skip)@E1 + b1)@E2 + b2 (A direct-loaded, gelu in-reg)
__global__ __launch_bounds__(256) void kend2(const u16* __restrict__ skip, const u16* __restrict__ Bt1,
                                             const u16* __restrict__ Bt2, const float* __restrict__ b1,
                                             const float* __restrict__ b2, u16* __restrict__ h2){
  __shared__ char sA[8192];
  int tid = threadIdx.x;
  int w = tid>>6, ln = tid&63, lr = ln&15, hi = ln>>4;
  int kboff = hi<<4;
  size_t r = (size_t)blockIdx.x*64 + w*16 + lr;
  const char* B1 = (const char*)Bt1;
  const char* B2 = (const char*)Bt2;
  f32x4 acc[4];
#pragma unroll
  for(int i=0;i<4;i++) acc[i] = f32x4{0.f,0.f,0.f,0.f};
#pragma unroll
  for(int kt=0; kt<2; ++kt){
    bf16x8 a = *reinterpret_cast<const bf16x8*>((const char*)skip + r*128 + kt*64 + kboff);
#pragma unroll
    for(int i=0;i<8;i++) a[i] = (short)f2bf(gelu_f(bf2f(a[i])));
#pragma unroll
    for(int nt=0; nt<4; ++nt){
      bf16x8 b = gldB(B1, nt*16 + lr, kt*64 + kboff, 128);
      acc[nt] = __builtin_amdgcn_mfma_f32_16x16x32_bf16(a, b, acc[nt], 0, 0, 0);
    }
  }
  u16 xq[4][4];
#pragma unroll
  for(int nt=0; nt<4; ++nt){
    int c = nt*16 + lr;
    float bv = b1[c];
#pragma unroll
    for(int rr=0;rr<4;++rr) xq[nt][rr] = f2bf(gelu_f(acc[nt][rr] + bv));
  }
#pragma unroll
  for(int nt=0; nt<4; ++nt){
    int col = nt*16 + lr;
#pragma unroll
    for(int rr=0;rr<4;++rr){
      int row = w*16 + hi*4 + rr;
      *(u16*)(sA + row*128 + ((col*2) ^ ((row&7)<<4))) = xq[nt][rr];
    }
  }
  __syncthreads();
  f32x4 a2[4];
#pragma unroll
  for(int i=0;i<4;i++) a2[i] = f32x4{0.f,0.f,0.f,0.f};
#pragma unroll
  for(int kt=0; kt<2; ++kt){
    bf16x8 a = lds16(sA, w*16 + lr, kt*64 + kboff, 128);
#pragma unroll
    for(int nt=0; nt<4; ++nt){
      bf16x8 b = gldB(B2, nt*16 + lr, kt*64 + kboff, 128);
      a2[nt] = __builtin_amdgcn_mfma_f32_16x16x32_bf16(a, b, a2[nt], 0, 0, 0);
    }
  }
  size_t rbase = (size_t)blockIdx.x*64 + w*16 + hi*4;
#pragma unroll
  for(int nt=0; nt<4; ++nt){
    int c = nt*16 + lr;
    float bv = b2[c];
#pragma unroll
    for(int rr=0;rr<4;++rr) h2[(rbase+rr)*64 + c] = f2bf(a2[nt][rr] + bv);
  }
}

// eeg1: (512 x 23680) @ (23680 x 256), split-K partials (deterministic, no atomics)
__global__ __launch_bounds__(512) void keeg1(const u16* __restrict__ h2, const u16* __restrict__ WtE,
                                             float* __restrict__ part){
  __shared__ char sA[64*128];    // 8KB
  __shared__ char sB[256*128];   // 32KB
  int rowg = blockIdx.x, sp = blockIdx.y;
  int tid = threadIdx.x, w = tid>>6, ln = tid&63;
  f32x4 acc[8];
#pragma unroll
  for(int i=0;i<8;i++) acc[i] = f32x4{0.f,0.f,0.f,0.f};
  int mt = w & 3, ntb = (w>>2)*8;
  for(int ks=0; ks<20; ++ks){
    int k0 = (sp*20 + ks)*32;
    __syncthreads();
    for(int s = tid; s < 256; s += 512){
      int row = s>>2, kc = s&3;
      bf16x8 v = *reinterpret_cast<const bf16x8*>(h2 + (size_t)(rowg*64+row)*23680 + k0 + kc*8);
      sts16(sA, row, kc*16, 128, v);
    }
    for(int s = tid; s < 1024; s += 512){
      int row = s>>2, kc = s&3;
      bf16x8 v = *reinterpret_cast<const bf16x8*>(WtE + (size_t)row*23680 + k0 + kc*8);
      sts16(sB, row, kc*16, 128, v);
    }
    __syncthreads();
    bf16x8 a = lds16(sA, mt*16 + (ln&15), ((ln>>4)<<4), 128);
#pragma unroll
    for(int j=0;j<8;++j){
      bf16x8 b = lds16(sB, (ntb+j)*16 + (ln&15), ((ln>>4)<<4), 128);
      acc[j] = __builtin_amdgcn_mfma_f32_16x16x32_bf16(a, b, acc[j], 0, 0, 0);
    }
  }
  float* dst = part + ((size_t)sp*512 + rowg*64)*256;
#pragma unroll
  for(int j=0;j<8;++j){
    int c = (ntb+j)*16 + (ln&15);
#pragma unroll
    for(int r=0;r<4;++r){
      int row = mt*16 + ((ln>>4)<<2) + r;
      dst[(size_t)row*256 + c] = acc[j][r];
    }
  }
}

// reduce partials + bias + gelu, then @ eeg2_W + b2 -> output (fp32)
__global__ __launch_bounds__(256) void keeg2(const float* __restrict__ part, const float* __restrict__ b1,
                                             const float* __restrict__ W2, const float* __restrict__ b2,
                                             float* __restrict__ out){
  __shared__ float u[256];
  __shared__ float pr[4][64];
  int bt = blockIdx.x, tid = threadIdx.x;
  float sacc = 0.f;
  for(int sp2=0; sp2<SPLITK; ++sp2) sacc += part[((size_t)sp2*512 + bt)*256 + tid];
  u[tid] = gelu_f(sacc + b1[tid]);
  __syncthreads();
  int w = tid>>6, ln = tid&63;
  float acc = 0.f;
  for(int c = w*64; c < (w+1)*64; ++c) acc += u[c] * W2[c*64 + ln];
  pr[w][ln] = acc;
  __syncthreads();
  if(tid < 64)
    out[(size_t)bt*64 + tid] = pr[0][tid]+pr[1][tid]+pr[2][tid]+pr[3][tid] + b2[tid];
}

// ---------- launcher ----------
extern "C" void kernel_launch(void* const* d_in, const int* in_sizes, int n_in,
                              void* d_out, int out_size, void* d_ws, size_t ws_size,
                              hipStream_t stream){
  const float* x_in  = (const float*)d_in[0];
  const int*   ei    = (const int*)d_in[1];
  const float* ew    = (const float*)d_in[2];
  const float* in_W  = (const float*)d_in[3];
  const float* in_b  = (const float*)d_in[4];
  const float* gcnfW = (const float*)d_in[5];
  const float* gcnfb = (const float*)d_in[6];
  const float* esrc  = (const float*)d_in[7];
  const float* etgt  = (const float*)d_in[8];
  const float* gcnaW = (const float*)d_in[9];
  const float* gcnab = (const float*)d_in[10];
  const float* filtW = (const float*)d_in[11];
  const float* filtb = (const float*)d_in[12];
  const float* gateW = (const float*)d_in[13];
  const float* gateb = (const float*)d_in[14];
  const float* resW  = (const float*)d_in[15];
  const float* resb  = (const float*)d_in[16];
  const float* skipW = (const float*)d_in[17];
  const float* skipb = (const float*)d_in[18];
  const float* lng   = (const float*)d_in[19];
  const float* lnb   = (const float*)d_in[20];
  const float* e1W   = (const float*)d_in[21];
  const float* e1b   = (const float*)d_in[22];
  const float* e2W   = (const float*)d_in[23];
  const float* e2b   = (const float*)d_in[24];
  const float* eg1W  = (const float*)d_in[25];
  const float* eg1b  = (const float*)d_in[26];
  const float* eg2W  = (const float*)d_in[27];
  const float* eg2b  = (const float*)d_in[28];
  int E = in_sizes[2];

  char* p = (char*)d_ws;
  auto carve = [&](size_t bytes)->char*{ char* r = p; p += (bytes + 255) & ~(size_t)255; return r; };
  u16*   xbf   = (u16*)  carve((size_t)RR*64*2);
  u16*   skip  = (u16*)  carve((size_t)RR*64*2);
  u16*   t2    = (u16*)  carve((size_t)RR*64*2);
  u16*   h2    = (u16*)  carve((size_t)RR*64*2);
  float* Araw9 = (float*)carve((size_t)9*NN*NN*4);   // [fixed | 8 adaptive raw]
  float* Araw  = Araw9;
  float* ArawA = Araw9 + (size_t)NN*NN;
  float* dinvF = (float*)carve(NN*4);
  float* dinvA = (float*)carve(LL*NN*4);
  u16*   Acat  = (u16*)  carve((size_t)LL*384*768*2);
  u16*   BtUV  = (u16*)  carve((size_t)LL*128*64*2);
  u16*   BtCV  = (u16*)  carve((size_t)LL*128*128*2);
  u16*   BtSR  = (u16*)  carve((size_t)LL*128*64*2);
  u16*   BtIN  = (u16*)  carve(64*64*2);
  u16*   BtE1  = (u16*)  carve(64*64*2);
  u16*   BtE2  = (u16*)  carve(64*64*2);
  u16*   WtE   = (u16*)  carve((size_t)256*23680*2);
  float* part  = (float*)carve((size_t)SPLITK*512*256*4);

  // --- prep ---
  kzero<<<1024, 256, 0, stream>>>(Araw9, (size_t)9*NN*NN);
  kbuildA<<<(E+255)/256, 256, 0, stream>>>(ei, ew, Araw, E);
  knormF<<<NN, 64, 0, stream>>>(Araw, dinvF);
  kadapt<<<dim3(NN, LL), 512, 0, stream>>>(esrc, etgt, ArawA, dinvA);
  kacat<<<(LL*384*768 + 255)/256, 256, 0, stream>>>(Araw, ArawA, dinvF, dinvA, Acat);
  kbt_small<<<3, 256, 0, stream>>>(in_W, e1W, e2W, BtIN, BtE1, BtE2);
  kbt_layer<<<dim3(LL, 3), 256, 0, stream>>>(gcnfW, gcnaW, filtW, gateW, skipW, resW, BtUV, BtCV, BtSR);
  ktrans<<<dim3(370, 4), 256, 0, stream>>>(eg1W, WtE);

  // --- input proj ---
  krowmm_in<<<RR/64, 256, 0, stream>>>(x_in, BtIN, in_b, xbf);

  // --- layers ---
  for(int l=0; l<LL; ++l){
    int dil = 1 << (l & 3);
    kgcn<<<dim3(2, BTOT), 256, 0, stream>>>(xbf, BtUV + (size_t)l*8192, Acat + (size_t)l*384*768,
                                            gcnfb + l*64, gcnab + l*64, t2);
    int douv = (l < LL-1) ? 1 : 0;
    kcsr<<<RR/64, 256, 0, stream>>>(t2, BtCV + (size_t)l*16384, BtSR + (size_t)l*8192,
                                    filtb + l*64, gateb + l*64, skipb + l*64, resb + l*64,
                                    lng + l*64, lnb + l*64, skip, xbf, dil, l==0 ? 1 : 0, douv);
  }

  // --- tail ---
  kend2<<<RR/64, 256, 0, stream>>>(skip, BtE1, BtE2, e1b, e2b, h2);
  keeg1<<<dim3(8, SPLITK), 512, 0, stream>>>(h2, WtE, part);
  keeg2<<<BTOT, 256, 0, stream>>>(part, eg1b, eg2W, eg2b, (float*)d_out);
}

// Round 15
// 952.270 us; speedup vs baseline: 1.1125x; 1.1125x over previous
//
#include <hip/hip_runtime.h>
#include <hip/hip_bf16.h>
#include <math.h>

typedef __attribute__((ext_vector_type(8))) short bf16x8;
typedef __attribute__((ext_vector_type(4))) float f32x4;
typedef unsigned short u16;
typedef unsigned int u32;
typedef unsigned long long u64;

#define NN 370
#define HH 64
#define LL 8
#define TT 64
#define BTOT 512            // B*T
#define RR (BTOT*NN)        // 189440 rows
#define KTOPK 37
#define SPLITK 37

// ---------- helpers ----------
__device__ inline u16 f2bf(float f){
  __hip_bfloat16 h = __float2bfloat16(f);
  return __builtin_bit_cast(u16, h);
}
__device__ inline float bf2f(short s){
  u32 v = ((u32)(u16)s) << 16;
  return __builtin_bit_cast(float, v);
}
__device__ inline float gelu_f(float x){ return 0.5f * x * (1.0f + erff(x * 0.70710678118654752440f)); }

// swizzled LDS store/load of 16B (8 bf16). stride must be a multiple of 128 bytes.
__device__ inline void sts16(char* lds, int row, int kb, int stride, bf16x8 v){
  *reinterpret_cast<bf16x8*>(lds + row*stride + (kb ^ ((row&7)<<4))) = v;
}
__device__ inline bf16x8 lds16(const char* lds, int row, int kb, int stride){
  return *reinterpret_cast<const bf16x8*>(lds + row*stride + (kb ^ ((row&7)<<4)));
}
// direct-global fragment load from pre-swizzled Bt[col][k] tile
__device__ inline bf16x8 gldB(const char* Bt, int c, int kb, int stride){
  return *reinterpret_cast<const bf16x8*>(Bt + c*stride + (kb ^ ((c&7)<<4)));
}

// ---------- prep kernels ----------
__global__ void kzero(float* __restrict__ p, size_t n){
  for(size_t i = (size_t)blockIdx.x*256 + threadIdx.x; i < n; i += (size_t)gridDim.x*256) p[i] = 0.f;
}

__global__ void kbuildA(const int* __restrict__ ei, const float* __restrict__ ew, float* __restrict__ Araw, int E){
  int e = blockIdx.x*256 + threadIdx.x;
  if(e < E){
    int src = ei[e], dst = ei[E + e];
    atomicAdd(&Araw[dst*NN + src], ew[e]);
  }
}

// parallel gcn-norm for fixed A: one block (64 lanes) per row
__global__ __launch_bounds__(64) void knormF(float* __restrict__ Araw, float* __restrict__ dinvF){
  int i = blockIdx.x, ln = threadIdx.x;
  float d0 = Araw[i*NN + i];
  float s = 0.f;
  for(int j = ln; j < NN; j += 64) s += Araw[i*NN + j];
#pragma unroll
  for(int o=1;o<64;o<<=1) s += __shfl_xor(s, o, 64);
  if(ln == 0){
    if(d0 == 0.f){ Araw[i*NN+i] = 1.f; s += 1.f; }
    dinvF[i] = rsqrtf(s);
  }
}

// adaptive adjacency: one block per (row i, layer l).
// Exact jax top_k via bitonic sort of packed (value,index) keys.
__global__ __launch_bounds__(512) void kadapt(const float* __restrict__ esrc, const float* __restrict__ etgt,
                                              float* __restrict__ ArawA, float* __restrict__ dinvA){
  __shared__ float tgT[16][372];
  __shared__ float red[8];
  __shared__ u64 keys[512];
  __shared__ int diagflag;
  int i = blockIdx.x, l = blockIdx.y, tid = threadIdx.x;
  const float* Et = etgt + (size_t)l*NN*16;
  for(int idx = tid; idx < NN*16; idx += 512)
    tgT[idx & 15][idx >> 4] = Et[idx];
  float sr[16];
  const float* Es = esrc + ((size_t)l*NN + i)*16;
#pragma unroll
  for(int k=0;k<16;k++) sr[k] = Es[k];
  if(tid == 0) diagflag = 0;
  __syncthreads();
  bool act = tid < NN;
  float s = 0.f;
  if(act){
    float d = 0.f;
#pragma unroll
    for(int k=0;k<16;k++) d += sr[k]*tgT[k][tid];
    s = fmaxf(d, 0.f);
  }
  float v = act ? s : -1.f;
#pragma unroll
  for(int o=1;o<64;o<<=1) v = fmaxf(v, __shfl_xor(v,o,64));
  if((tid&63)==0) red[tid>>6] = v;
  __syncthreads();
  float mx = red[0];
#pragma unroll
  for(int q=1;q<8;q++) mx = fmaxf(mx, red[q]);
  __syncthreads();
  float e = act ? expf(s - mx) : 0.f;
  float t = e;
#pragma unroll
  for(int o=1;o<64;o<<=1) t += __shfl_xor(t,o,64);
  if((tid&63)==0) red[tid>>6] = t;
  __syncthreads();
  float sum = 0.f;
#pragma unroll
  for(int q=0;q<8;q++) sum += red[q];
  float p = e / sum;
  u32 fb = __builtin_bit_cast(u32, p);
  keys[tid] = act ? ((((u64)fb)<<32) | (u64)(0xFFFFFFFFu - (u32)tid)) : 0ULL;
  __syncthreads();
  for(int k2=2; k2<=512; k2<<=1){
    for(int j=k2>>1; j>0; j>>=1){
      int ixj = tid ^ j;
      if(ixj > tid){
        u64 a = keys[tid], b = keys[ixj];
        bool dirUp = ((tid & k2) == 0);
        if(dirUp ? (a < b) : (a > b)){ keys[tid] = b; keys[ixj] = a; }
      }
      __syncthreads();
    }
  }
  float myval = 0.f; int myidx = -1;
  if(tid < KTOPK){
    u64 kk = keys[tid];
    myidx = (int)(0xFFFFFFFFu - (u32)kk);
    myval = __builtin_bit_cast(float, (u32)(kk>>32));
    if(myidx == i) diagflag = 1;
  }
  __syncthreads();
  float dsum = (tid < KTOPK) ? myval : 0.f;
  if(tid < 64){
#pragma unroll
    for(int o=1;o<64;o<<=1) dsum += __shfl_xor(dsum,o,64);
    if(tid == 0) dinvA[l*NN + i] = rsqrtf(dsum + (diagflag ? 0.f : 1.f));
  }
  if(tid < KTOPK) ArawA[((size_t)l*NN + i)*NN + myidx] = myval;
  if(tid == 0 && !diagflag) ArawA[((size_t)l*NN + i)*NN + i] = 1.f;
}

// build normalized dense bf16 A_cat[l] = [A_fixed(384) | A_adapt(384)] over k=768
__global__ void kacat(const float* __restrict__ Araw, const float* __restrict__ ArawA,
                      const float* __restrict__ dinvF, const float* __restrict__ dinvA,
                      u16* __restrict__ Acat){
  int idx = blockIdx.x*256 + threadIdx.x;
  if(idx >= LL*384*768) return;
  int k = idx % 768; int m = (idx / 768) % 384; int l = idx / (768*384);
  float v = 0.f;
  if(m < NN){
    if(k < 384){
      if(k < NN) v = dinvF[m]*Araw[m*NN+k]*dinvF[k];
    } else {
      int n = k - 384;
      if(n < NN) v = dinvA[l*NN+m]*ArawA[((size_t)l*NN+m)*NN+n]*dinvA[l*NN+n];
    }
  }
  Acat[idx] = f2bf(v);
}

// pre-transposed + pre-swizzled weight tiles Bt[col][k]
__global__ void kbt_small(const float* __restrict__ inW, const float* __restrict__ e1W, const float* __restrict__ e2W,
                          u16* __restrict__ BtIN, u16* __restrict__ BtE1, u16* __restrict__ BtE2){
  const float* W = blockIdx.x==0 ? inW : (blockIdx.x==1 ? e1W : e2W);
  u16* Bt = blockIdx.x==0 ? BtIN : (blockIdx.x==1 ? BtE1 : BtE2);
  for(int idx = threadIdx.x; idx < 4096; idx += 256){
    int c = idx >> 6, k = idx & 63;
    *(u16*)((char*)Bt + c*128 + ((k*2) ^ ((c&7)<<4))) = f2bf(W[k*64 + c]);
  }
}

__global__ void kbt_layer(const float* __restrict__ gcnfW, const float* __restrict__ gcnaW,
                          const float* __restrict__ filtW, const float* __restrict__ gateW,
                          const float* __restrict__ skipW, const float* __restrict__ resW,
                          u16* __restrict__ BtUV, u16* __restrict__ BtCV, u16* __restrict__ BtSR){
  int l = blockIdx.x, which = blockIdx.y;
  if(which == 0){            // [Wf | Wa] : 128 cols x 64 k
    u16* Bt = BtUV + (size_t)l*128*64;
    for(int idx=threadIdx.x; idx<8192; idx+=256){
      int c = idx>>6, k = idx&63;
      float v = (c<64) ? gcnfW[(size_t)l*4096 + k*64 + c] : gcnaW[(size_t)l*4096 + k*64 + (c-64)];
      *(u16*)((char*)Bt + c*128 + ((k*2) ^ ((c&7)<<4))) = f2bf(v);
    }
  } else if(which == 1){     // conv [filt | gate] : 128 cols x 128 k
    u16* Bt = BtCV + (size_t)l*128*128;
    for(int idx=threadIdx.x; idx<16384; idx+=256){
      int c = idx>>7, k = idx&127;
      const float* W = (c<64) ? filtW : gateW;
      int o = c & 63, ii = k & 63, tap = (k<64) ? 1 : 0;
      float v = W[(size_t)l*8192 + o*128 + ii*2 + tap];
      *(u16*)((char*)Bt + c*256 + ((k*2) ^ ((c&7)<<4))) = f2bf(v);
    }
  } else {                   // [skip | res] : 128 cols x 64 k
    u16* Bt = BtSR + (size_t)l*128*64;
    for(int idx=threadIdx.x; idx<8192; idx+=256){
      int c = idx>>6, k = idx&63;
      float v = (c<64) ? skipW[(size_t)l*4096 + c*64 + k] : resW[(size_t)l*4096 + (c-64)*64 + k];
      *(u16*)((char*)Bt + c*128 + ((k*2) ^ ((c&7)<<4))) = f2bf(v);
    }
  }
}

// eeg1_W (23680x256 fp32) -> Wt (256 x 23680 bf16)
__global__ void ktrans(const float* __restrict__ W, u16* __restrict__ Wt){
  __shared__ float tile[64][65];
  int kb = blockIdx.x*64, cb = blockIdx.y*64;
  for(int idx = threadIdx.x; idx < 4096; idx += 256){
    int kk = idx>>6, cc = idx&63;
    tile[kk][cc] = W[(size_t)(kb+kk)*256 + cb+cc];
  }
  __syncthreads();
  for(int idx = threadIdx.x; idx < 4096; idx += 256){
    int cc = idx>>6, kk = idx&63;
    Wt[(size_t)(cb+cc)*23680 + kb+kk] = f2bf(tile[kk][cc]);
  }
}

// ---------- main pipeline kernels ----------
// input proj: x = X@inW+b -> xbf (bf16). LDS-free: A fragments converted in-reg.
__global__ __launch_bounds__(256) void krowmm_in(const float* __restrict__ X, const u16* __restrict__ Bt,
                                                 const float* __restrict__ bias,
                                                 u16* __restrict__ xbf){
  int tid = threadIdx.x;
  int w = tid>>6, ln = tid&63, lr = ln&15, hi = ln>>4;
  int kboff = hi<<4;
  size_t r = (size_t)blockIdx.x*64 + w*16 + lr;
  f32x4 acc[4];
#pragma unroll
  for(int i=0;i<4;i++) acc[i] = f32x4{0.f,0.f,0.f,0.f};
  const char* BI = (const char*)Bt;
#pragma unroll
  for(int kt=0; kt<2; ++kt){
    const float* xr = X + r*64 + kt*32 + hi*8;
    float4 pa = ((const float4*)xr)[0], pb = ((const float4*)xr)[1];
    bf16x8 a;
    a[0]=(short)f2bf(pa.x); a[1]=(short)f2bf(pa.y); a[2]=(short)f2bf(pa.z); a[3]=(short)f2bf(pa.w);
    a[4]=(short)f2bf(pb.x); a[5]=(short)f2bf(pb.y); a[6]=(short)f2bf(pb.z); a[7]=(short)f2bf(pb.w);
#pragma unroll
    for(int nt=0; nt<4; ++nt){
      bf16x8 b = gldB(BI, nt*16 + lr, kt*64 + kboff, 128);
      acc[nt] = __builtin_amdgcn_mfma_f32_16x16x32_bf16(a, b, acc[nt], 0, 0, 0);
    }
  }
  size_t r0 = (size_t)blockIdx.x*64;
#pragma unroll
  for(int nt=0; nt<4; ++nt){
    int c = nt*16 + lr;
    float bv = bias[c];
#pragma unroll
    for(int rr=0;rr<4;++rr){
      int row = w*16 + hi*4 + rr;
      xbf[(r0+row)*64 + c] = f2bf(acc[nt][rr] + bv);
    }
  }
}

// per-(b,t): UV^T computed in-kernel from xbf, then OUT = A_cat @ [U;V] + biases.
// R13 structure + (a) p=0 skips the writer barrier, (b) kt=0,1 Acat fragments
// prefetched before the barrier so the A-loop starts MFMAs immediately.
__global__ __launch_bounds__(512) void kgcn(const u16* __restrict__ xbf, const u16* __restrict__ BtUV,
                                            const u16* __restrict__ Acat,
                                            const float* __restrict__ bfb, const float* __restrict__ bab,
                                            u16* __restrict__ t2){
  __shared__ char uvt[64*768];   // 48KB: one phase of UV^T [h=64][node 384]
  int bt = blockIdx.x, tid = threadIdx.x;
  int w = tid>>6, ln = tid&63, lr = ln&15, hi = ln>>4;
  int kboff = hi<<4;
  f32x4 acc[12];
#pragma unroll
  for(int j=0;j<12;j++) acc[j] = f32x4{0.f,0.f,0.f,0.f};
  const char* xb = (const char*)(xbf + (size_t)bt*NN*64);
#pragma unroll
  for(int p=0; p<2; ++p){
    // --- UV phase p ---
    bf16x8 bw[2][4];
#pragma unroll
    for(int kt=0;kt<2;++kt)
#pragma unroll
      for(int nt=0;nt<4;++nt){
        int c = p*64 + nt*16 + lr;
        bw[kt][nt] = *reinterpret_cast<const bf16x8*>((const char*)BtUV + c*128 + ((kt*64 + kboff) ^ ((c&7)<<4)));
      }
    f32x4 uvacc[3][4];
#pragma unroll
    for(int mi=0;mi<3;++mi)
#pragma unroll
      for(int nt=0;nt<4;++nt) uvacc[mi][nt] = f32x4{0.f,0.f,0.f,0.f};
#pragma unroll
    for(int mi=0;mi<3;++mi){
      int node = (w*3+mi)*16 + lr;
#pragma unroll
      for(int kt=0;kt<2;++kt){
        bf16x8 a;
        if(node < NN) a = *reinterpret_cast<const bf16x8*>(xb + (size_t)node*128 + kt*64 + kboff);
        else { bf16x8 z = {0,0,0,0,0,0,0,0}; a = z; }
#pragma unroll
        for(int nt=0;nt<4;++nt)
          uvacc[mi][nt] = __builtin_amdgcn_mfma_f32_16x16x32_bf16(a, bw[kt][nt], uvacc[mi][nt], 0,0,0);
      }
    }
    // prefetch kt=0,1 A-fragments (latency hides under store+barrier drain)
    const char* abase = (const char*)Acat + p*768 + kboff;
    bf16x8 pa0[3], pa1[3];
#pragma unroll
    for(int mi=0;mi<3;++mi){
      pa0[mi] = *reinterpret_cast<const bf16x8*>(abase + (size_t)((w*3+mi)*16 + lr)*1536);
      pa1[mi] = *reinterpret_cast<const bf16x8*>(abase + (size_t)((w*3+mi)*16 + lr)*1536 + 64);
    }
    if(p) __syncthreads();   // previous phase's A-loop readers done (p=0: no readers yet)
#pragma unroll
    for(int mi=0;mi<3;++mi){
      int nd = (w*3+mi)*16 + hi*4;
#pragma unroll
      for(int nt=0;nt<4;++nt){
        int cl = nt*16 + lr;
        u64 pk = (u64)((u32)f2bf(uvacc[mi][nt][0]) | ((u32)f2bf(uvacc[mi][nt][1])<<16))
               | ((u64)((u32)f2bf(uvacc[mi][nt][2]) | ((u32)f2bf(uvacc[mi][nt][3])<<16)) << 32);
        *(u64*)(uvt + cl*768 + ((nd*2) ^ ((cl&7)<<4))) = pk;
      }
    }
    __syncthreads();
    // --- A-loop phase p ---
    __builtin_amdgcn_s_setprio(1);
#pragma unroll
    for(int kt=0; kt<12; ++kt){
      bf16x8 a0, a1, a2;
      if(kt == 0){ a0 = pa0[0]; a1 = pa0[1]; a2 = pa0[2]; }
      else if(kt == 1){ a0 = pa1[0]; a1 = pa1[1]; a2 = pa1[2]; }
      else {
        a0 = *reinterpret_cast<const bf16x8*>(abase + (size_t)((w*3+0)*16 + lr)*1536 + kt*64);
        a1 = *reinterpret_cast<const bf16x8*>(abase + (size_t)((w*3+1)*16 + lr)*1536 + kt*64);
        a2 = *reinterpret_cast<const bf16x8*>(abase + (size_t)((w*3+2)*16 + lr)*1536 + kt*64);
      }
      bf16x8 b0 = lds16(uvt, 0*16 + lr, kt*64 + kboff, 768);
      bf16x8 b1 = lds16(uvt, 1*16 + lr, kt*64 + kboff, 768);
      bf16x8 b2 = lds16(uvt, 2*16 + lr, kt*64 + kboff, 768);
      bf16x8 b3 = lds16(uvt, 3*16 + lr, kt*64 + kboff, 768);
      acc[0]  = __builtin_amdgcn_mfma_f32_16x16x32_bf16(a0, b0, acc[0],  0,0,0);
      acc[1]  = __builtin_amdgcn_mfma_f32_16x16x32_bf16(a0, b1, acc[1],  0,0,0);
      acc[2]  = __builtin_amdgcn_mfma_f32_16x16x32_bf16(a0, b2, acc[2],  0,0,0);
      acc[3]  = __builtin_amdgcn_mfma_f32_16x16x32_bf16(a0, b3, acc[3],  0,0,0);
      acc[4]  = __builtin_amdgcn_mfma_f32_16x16x32_bf16(a1, b0, acc[4],  0,0,0);
      acc[5]  = __builtin_amdgcn_mfma_f32_16x16x32_bf16(a1, b1, acc[5],  0,0,0);
      acc[6]  = __builtin_amdgcn_mfma_f32_16x16x32_bf16(a1, b2, acc[6],  0,0,0);
      acc[7]  = __builtin_amdgcn_mfma_f32_16x16x32_bf16(a1, b3, acc[7],  0,0,0);
      acc[8]  = __builtin_amdgcn_mfma_f32_16x16x32_bf16(a2, b0, acc[8],  0,0,0);
      acc[9]  = __builtin_amdgcn_mfma_f32_16x16x32_bf16(a2, b1, acc[9],  0,0,0);
      acc[10] = __builtin_amdgcn_mfma_f32_16x16x32_bf16(a2, b2, acc[10], 0,0,0);
      acc[11] = __builtin_amdgcn_mfma_f32_16x16x32_bf16(a2, b3, acc[11], 0,0,0);
    }
    __builtin_amdgcn_s_setprio(0);
  }
#pragma unroll
  for(int mi=0; mi<3; ++mi){
    int mt = w*3 + mi;
    int mbase = mt*16 + hi*4;
#pragma unroll
    for(int nt=0; nt<4; ++nt){
      int col = nt*16 + lr;
      float bias = bfb[col] + bab[col];
#pragma unroll
      for(int r=0;r<4;++r){
        int m = mbase + r;
        if(m < NN) t2[((size_t)bt*NN + m)*64 + col] = f2bf(acc[mi*4+nt][r] + bias);
      }
    }
  }
}

// fused: gated causal conv + skip/res 1x1 + residual + LayerNorm + skip accum.
// Conv A direct from global; B direct from L1/L2. Two DISJOINT LDS stages
// (act bf16 8KB @0, skip/res bf16 16KB @8KB) -> only 2 barriers, 24KB total.
__global__ __launch_bounds__(256) void kcsr(const u16* __restrict__ t2, const u16* __restrict__ BtC,
                                            const u16* __restrict__ BtS,
                                            const float* __restrict__ fb, const float* __restrict__ gb,
                                            const float* __restrict__ sb, const float* __restrict__ rb,
                                            const float* __restrict__ lng, const float* __restrict__ lnb,
                                            u16* __restrict__ skip,
                                            u16* __restrict__ xbf, int dil, int first, int douv){
  __shared__ char sA[24576];
  char* sact = sA;           // [64][128B] bf16 activation stage
  char* ssr  = sA + 8192;    // [64][256B] bf16 skip(0..63)/res(64..127) stage
  int blk = blockIdx.x, tid = threadIdx.x;
  int w = tid>>6, ln = tid&63, lr = ln&15, hi = ln>>4;
  int kboff = hi<<4;
  int r0 = blk*64;
  int r = r0 + w*16 + lr;                 // this thread's conv row
  int t = (r / NN) & (TT-1);              // time index of this row
  const char* cur = (const char*)t2 + (size_t)r*128;
  const char* prv = cur - (size_t)dil*NN*128;
  bf16x8 a0 = *reinterpret_cast<const bf16x8*>(cur + kboff);
  bf16x8 a1 = *reinterpret_cast<const bf16x8*>(cur + 64 + kboff);
  bf16x8 a2, a3;
  if(t >= dil){
    a2 = *reinterpret_cast<const bf16x8*>(prv + kboff);
    a3 = *reinterpret_cast<const bf16x8*>(prv + 64 + kboff);
  } else {
    bf16x8 z = {0,0,0,0,0,0,0,0}; a2 = z; a3 = z;
  }
  const char* BC = (const char*)BtC;
  f32x4 acc[8];
#pragma unroll
  for(int i=0;i<8;i++) acc[i] = f32x4{0.f,0.f,0.f,0.f};
  bf16x8 afr[4] = {a0, a1, a2, a3};
#pragma unroll
  for(int kt=0; kt<4; ++kt){
    bf16x8 bfr[8];
#pragma unroll
    for(int nt=0; nt<8; ++nt)
      bfr[nt] = gldB(BC, nt*16 + lr, kt*64 + kboff, 256);
#pragma unroll
    for(int nt=0; nt<8; ++nt)
      acc[nt] = __builtin_amdgcn_mfma_f32_16x16x32_bf16(afr[kt], bfr[nt], acc[nt], 0, 0, 0);
  }
  u16 qv[4][4];
#pragma unroll
  for(int nt=0; nt<4; ++nt){
    int o = nt*16 + lr;
    float fbv = fb[o], gbv = gb[o];
#pragma unroll
    for(int rr=0;rr<4;++rr){
      float fv = acc[nt][rr] + fbv;
      float gv = acc[nt+4][rr] + gbv;
      float ef = __expf(-2.f*fv);
      float th = (1.f - ef) * __builtin_amdgcn_rcpf(1.f + ef);
      float sg = __builtin_amdgcn_rcpf(1.f + __expf(-gv));
      qv[nt][rr] = f2bf(th * sg);
    }
  }
#pragma unroll
  for(int nt=0; nt<4; ++nt){
    int col = nt*16 + lr;
#pragma unroll
    for(int rr=0;rr<4;++rr){
      int row = w*16 + hi*4 + rr;
      *(u16*)(sact + row*128 + ((col*2) ^ ((row&7)<<4))) = qv[nt][rr];
    }
  }
  __syncthreads();
  const char* BS = (const char*)BtS;
  f32x4 as[8];
#pragma unroll
  for(int i=0;i<8;i++) as[i] = f32x4{0.f,0.f,0.f,0.f};
#pragma unroll
  for(int kt=0; kt<2; ++kt){
    bf16x8 a = lds16(sact, w*16 + lr, kt*64 + kboff, 128);
    bf16x8 bfr[8];
#pragma unroll
    for(int nt=0; nt<8; ++nt)
      bfr[nt] = gldB(BS, nt*16 + lr, kt*64 + kboff, 128);
#pragma unroll
    for(int nt=0; nt<8; ++nt)
      as[nt] = __builtin_amdgcn_mfma_f32_16x16x32_bf16(a, bfr[nt], as[nt], 0, 0, 0);
  }
  // as[0..3] = skip cols (0..63), as[4..7] = res cols (0..63)
  // write to DISJOINT sr region (no barrier needed: act readers unaffected)
#pragma unroll
  for(int nt=0; nt<4; ++nt){
    int c = nt*16 + lr;
#pragma unroll
    for(int rr=0;rr<4;++rr){
      int row = w*16 + hi*4 + rr;
      *(u16*)(ssr + row*256 + (((c)*2)      ^ ((row&7)<<4))) = f2bf(as[nt][rr]);
      *(u16*)(ssr + row*256 + (((64+c)*2)   ^ ((row&7)<<4))) = f2bf(as[4+nt][rr]);
    }
  }
  __syncthreads();
  // ---- row-major epilogue: thread = (row = tid>>2, 16-col segment = tid&3) ----
  int row = tid >> 2, seg = tid & 3;
  int c0 = seg * 16;
  bf16x8 vs0 = *reinterpret_cast<const bf16x8*>(ssr + row*256 + (((c0)*2)      ^ ((row&7)<<4)));
  bf16x8 vs1 = *reinterpret_cast<const bf16x8*>(ssr + row*256 + (((c0+8)*2)    ^ ((row&7)<<4)));
  bf16x8 vr0 = *reinterpret_cast<const bf16x8*>(ssr + row*256 + (((64+c0)*2)   ^ ((row&7)<<4)));
  bf16x8 vr1 = *reinterpret_cast<const bf16x8*>(ssr + row*256 + (((64+c0+8)*2) ^ ((row&7)<<4)));
  float sk[16], re[16];
#pragma unroll
  for(int i=0;i<8;++i){ sk[i] = bf2f(vs0[i]); sk[8+i] = bf2f(vs1[i]); }
#pragma unroll
  for(int i=0;i<8;++i){ re[i] = bf2f(vr0[i]); re[8+i] = bf2f(vr1[i]); }
  size_t gr = (size_t)(r0 + row)*64 + c0;
  bf16x8 xv0 = *reinterpret_cast<const bf16x8*>(xbf + gr);
  bf16x8 xv1 = *reinterpret_cast<const bf16x8*>(xbf + gr + 8);
  float y[16]; float s1 = 0.f, s2 = 0.f;
#pragma unroll
  for(int i=0;i<16;++i){
    float xo = bf2f(i < 8 ? xv0[i] : xv1[i-8]);
    float vv = re[i] + rb[c0+i] + xo;
    y[i] = vv; s1 += vv; s2 += vv*vv;
  }
  s1 += __shfl_xor(s1, 1, 64); s1 += __shfl_xor(s1, 2, 64);
  s2 += __shfl_xor(s2, 1, 64); s2 += __shfl_xor(s2, 2, 64);
  float m = s1 * (1.f/64.f);
  float var = s2 * (1.f/64.f) - m*m;
  float rstd = rsqrtf(var + 1e-5f);
  if(douv){
    bf16x8 o0, o1;
#pragma unroll
    for(int i=0;i<16;++i){
      float xo = (y[i] - m) * rstd * lng[c0+i] + lnb[c0+i];
      if(i < 8) o0[i] = (short)f2bf(xo); else o1[i-8] = (short)f2bf(xo);
    }
    *reinterpret_cast<bf16x8*>(xbf + gr) = o0;
    *reinterpret_cast<bf16x8*>(xbf + gr + 8) = o1;
  }
  bf16x8 so0, so1;
  if(first){
#pragma unroll
    for(int i=0;i<16;++i){
      float sv = sk[i] + sb[c0+i];
      if(i < 8) so0[i] = (short)f2bf(sv); else so1[i-8] = (short)f2bf(sv);
    }
  } else {
    bf16x8 sp0 = *reinterpret_cast<const bf16x8*>(skip + gr);
    bf16x8 sp1 = *reinterpret_cast<const bf16x8*>(skip + gr + 8);
#pragma unroll
    for(int i=0;i<16;++i){
      float old = bf2f(i < 8 ? sp0[i] : sp1[i-8]);
      float sv = old + sk[i] + sb[c0+i];
      if(i < 8) so0[i] = (short)f2bf(sv); else so1[i-8] = (short)f2bf(sv);
    }
  }
  *reinterpret_cast<bf16x8*>(skip + gr) = so0;
  *reinterpret_cast<bf16x8*>(skip + gr + 8) = so1;
}

// fused end convs: h2 = gelu(gelu(skip)@E1 + b1)@E2 + b2 (A direct-loaded, gelu in-reg)
__global__ __launch_bounds__(256) void kend2(const u16* __restrict__ skip, const u16* __restrict__ Bt1,
                                             const u16* __restrict__ Bt2, const float* __restrict__ b1,
                                             const float* __restrict__ b2, u16* __restrict__ h2){
  __shared__ char sA[8192];
  int tid = threadIdx.x;
  int w = tid>>6, ln = tid&63, lr = ln&15, hi = ln>>4;
  int kboff = hi<<4;
  size_t r = (size_t)blockIdx.x*64 + w*16 + lr;
  const char* B1 = (const char*)Bt1;
  const char* B2 = (const char*)Bt2;
  f32x4 acc[4];
#pragma unroll
  for(int i=0;i<4;i++) acc[i] = f32x4{0.f,0.f,0.f,0.f};
#pragma unroll
  for(int kt=0; kt<2; ++kt){
    bf16x8 a = *reinterpret_cast<const bf16x8*>((const char*)skip + r*128 + kt*64 + kboff);
#pragma unroll
    for(int i=0;i<8;i++) a[i] = (short)f2bf(gelu_f(bf2f(a[i])));
#pragma unroll
    for(int nt=0; nt<4; ++nt){
      bf16x8 b = gldB(B1, nt*16 + lr, kt*64 + kboff, 128);
      acc[nt] = __builtin_amdgcn_mfma_f32_16x16x32_bf16(a, b, acc[nt], 0, 0, 0);
    }
  }
  u16 xq[4][4];
#pragma unroll
  for(int nt=0; nt<4; ++nt){
    int c = nt*16 + lr;
    float bv = b1[c];
#pragma unroll
    for(int rr=0;rr<4;++rr) xq[nt][rr] = f2bf(gelu_f(acc[nt][rr] + bv));
  }
#pragma unroll
  for(int nt=0; nt<4; ++nt){
    int col = nt*16 + lr;
#pragma unroll
    for(int rr=0;rr<4;++rr){
      int row = w*16 + hi*4 + rr;
      *(u16*)(sA + row*128 + ((col*2) ^ ((row&7)<<4))) = xq[nt][rr];
    }
  }
  __syncthreads();
  f32x4 a2[4];
#pragma unroll
  for(int i=0;i<4;i++) a2[i] = f32x4{0.f,0.f,0.f,0.f};
#pragma unroll
  for(int kt=0; kt<2; ++kt){
    bf16x8 a = lds16(sA, w*16 + lr, kt*64 + kboff, 128);
#pragma unroll
    for(int nt=0; nt<4; ++nt){
      bf16x8 b = gldB(B2, nt*16 + lr, kt*64 + kboff, 128);
      a2[nt] = __builtin_amdgcn_mfma_f32_16x16x32_bf16(a, b, a2[nt], 0, 0, 0);
    }
  }
  size_t rbase = (size_t)blockIdx.x*64 + w*16 + hi*4;
#pragma unroll
  for(int nt=0; nt<4; ++nt){
    int c = nt*16 + lr;
    float bv = b2[c];
#pragma unroll
    for(int rr=0;rr<4;++rr) h2[(rbase+rr)*64 + c] = f2bf(a2[nt][rr] + bv);
  }
}

// eeg1: (512 x 23680) @ (23680 x 256), split-K partials (deterministic, no atomics)
__global__ __launch_bounds__(512) void keeg1(const u16* __restrict__ h2, const u16* __restrict__ WtE,
                                             float* __restrict__ part){
  __shared__ char sA[64*128];    // 8KB
  __shared__ char sB[256*128];   // 32KB
  int rowg = blockIdx.x, sp = blockIdx.y;
  int tid = threadIdx.x, w = tid>>6, ln = tid&63;
  f32x4 acc[8];
#pragma unroll
  for(int i=0;i<8;i++) acc[i] = f32x4{0.f,0.f,0.f,0.f};
  int mt = w & 3, ntb = (w>>2)*8;
  for(int ks=0; ks<20; ++ks){
    int k0 = (sp*20 + ks)*32;
    __syncthreads();
    for(int s = tid; s < 256; s += 512){
      int row = s>>2, kc = s&3;
      bf16x8 v = *reinterpret_cast<const bf16x8*>(h2 + (size_t)(rowg*64+row)*23680 + k0 + kc*8);
      sts16(sA, row, kc*16, 128, v);
    }
    for(int s = tid; s < 1024; s += 512){
      int row = s>>2, kc = s&3;
      bf16x8 v = *reinterpret_cast<const bf16x8*>(WtE + (size_t)row*23680 + k0 + kc*8);
      sts16(sB, row, kc*16, 128, v);
    }
    __syncthreads();
    bf16x8 a = lds16(sA, mt*16 + (ln&15), ((ln>>4)<<4), 128);
#pragma unroll
    for(int j=0;j<8;++j){
      bf16x8 b = lds16(sB, (ntb+j)*16 + (ln&15), ((ln>>4)<<4), 128);
      acc[j] = __builtin_amdgcn_mfma_f32_16x16x32_bf16(a, b, acc[j], 0, 0, 0);
    }
  }
  float* dst = part + ((size_t)sp*512 + rowg*64)*256;
#pragma unroll
  for(int j=0;j<8;++j){
    int c = (ntb+j)*16 + (ln&15);
#pragma unroll
    for(int r=0;r<4;++r){
      int row = mt*16 + ((ln>>4)<<2) + r;
      dst[(size_t)row*256 + c] = acc[j][r];
    }
  }
}

// reduce partials + bias + gelu, then @ eeg2_W + b2 -> output (fp32)
__global__ __launch_bounds__(256) void keeg2(const float* __restrict__ part, const float* __restrict__ b1,
                                             const float* __restrict__ W2, const float* __restrict__ b2,
                                             float* __restrict__ out){
  __shared__ float u[256];
  __shared__ float pr[4][64];
  int bt = blockIdx.x, tid = threadIdx.x;
  float sacc = 0.f;
  for(int sp2=0; sp2<SPLITK; ++sp2) sacc += part[((size_t)sp2*512 + bt)*256 + tid];
  u[tid] = gelu_f(sacc + b1[tid]);
  __syncthreads();
  int w = tid>>6, ln = tid&63;
  float acc = 0.f;
  for(int c = w*64; c < (w+1)*64; ++c) acc += u[c] * W2[c*64 + ln];
  pr[w][ln] = acc;
  __syncthreads();
  if(tid < 64)
    out[(size_t)bt*64 + tid] = pr[0][tid]+pr[1][tid]+pr[2][tid]+pr[3][tid] + b2[tid];
}

// ---------- launcher ----------
extern "C" void kernel_launch(void* const* d_in, const int* in_sizes, int n_in,
                              void* d_out, int out_size, void* d_ws, size_t ws_size,
                              hipStream_t stream){
  const float* x_in  = (const float*)d_in[0];
  const int*   ei    = (const int*)d_in[1];
  const float* ew    = (const float*)d_in[2];
  const float* in_W  = (const float*)d_in[3];
  const float* in_b  = (const float*)d_in[4];
  const float* gcnfW = (const float*)d_in[5];
  const float* gcnfb = (const float*)d_in[6];
  const float* esrc  = (const float*)d_in[7];
  const float* etgt  = (const float*)d_in[8];
  const float* gcnaW = (const float*)d_in[9];
  const float* gcnab = (const float*)d_in[10];
  const float* filtW = (const float*)d_in[11];
  const float* filtb = (const float*)d_in[12];
  const float* gateW = (const float*)d_in[13];
  const float* gateb = (const float*)d_in[14];
  const float* resW  = (const float*)d_in[15];
  const float* resb  = (const float*)d_in[16];
  const float* skipW = (const float*)d_in[17];
  const float* skipb = (const float*)d_in[18];
  const float* lng   = (const float*)d_in[19];
  const float* lnb   = (const float*)d_in[20];
  const float* e1W   = (const float*)d_in[21];
  const float* e1b   = (const float*)d_in[22];
  const float* e2W   = (const float*)d_in[23];
  const float* e2b   = (const float*)d_in[24];
  const float* eg1W  = (const float*)d_in[25];
  const float* eg1b  = (const float*)d_in[26];
  const float* eg2W  = (const float*)d_in[27];
  const float* eg2b  = (const float*)d_in[28];
  int E = in_sizes[2];

  char* p = (char*)d_ws;
  auto carve = [&](size_t bytes)->char*{ char* r = p; p += (bytes + 255) & ~(size_t)255; return r; };
  u16*   xbf   = (u16*)  carve((size_t)RR*64*2);
  u16*   skip  = (u16*)  carve((size_t)RR*64*2);
  u16*   t2    = (u16*)  carve((size_t)RR*64*2);
  u16*   h2    = (u16*)  carve((size_t)RR*64*2);
  float* Araw9 = (float*)carve((size_t)9*NN*NN*4);   // [fixed | 8 adaptive raw]
  float* Araw  = Araw9;
  float* ArawA = Araw9 + (size_t)NN*NN;
  float* dinvF = (float*)carve(NN*4);
  float* dinvA = (float*)carve(LL*NN*4);
  u16*   Acat  = (u16*)  carve((size_t)LL*384*768*2);
  u16*   BtUV  = (u16*)  carve((size_t)LL*128*64*2);
  u16*   BtCV  = (u16*)  carve((size_t)LL*128*128*2);
  u16*   BtSR  = (u16*)  carve((size_t)LL*128*64*2);
  u16*   BtIN  = (u16*)  carve(64*64*2);
  u16*   BtE1  = (u16*)  carve(64*64*2);
  u16*   BtE2  = (u16*)  carve(64*64*2);
  u16*   WtE   = (u16*)  carve((size_t)256*23680*2);
  float* part  = (float*)carve((size_t)SPLITK*512*256*4);

  // --- prep ---
  kzero<<<1024, 256, 0, stream>>>(Araw9, (size_t)9*NN*NN);
  kbuildA<<<(E+255)/256, 256, 0, stream>>>(ei, ew, Araw, E);
  knormF<<<NN, 64, 0, stream>>>(Araw, dinvF);
  kadapt<<<dim3(NN, LL), 512, 0, stream>>>(esrc, etgt, ArawA, dinvA);
  kacat<<<(LL*384*768 + 255)/256, 256, 0, stream>>>(Araw, ArawA, dinvF, dinvA, Acat);
  kbt_small<<<3, 256, 0, stream>>>(in_W, e1W, e2W, BtIN, BtE1, BtE2);
  kbt_layer<<<dim3(LL, 3), 256, 0, stream>>>(gcnfW, gcnaW, filtW, gateW, skipW, resW, BtUV, BtCV, BtSR);
  ktrans<<<dim3(370, 4), 256, 0, stream>>>(eg1W, WtE);

  // --- input proj ---
  krowmm_in<<<RR/64, 256, 0, stream>>>(x_in, BtIN, in_b, xbf);

  // --- layers ---
  for(int l=0; l<LL; ++l){
    int dil = 1 << (l & 3);
    kgcn<<<BTOT, 512, 0, stream>>>(xbf, BtUV + (size_t)l*8192, Acat + (size_t)l*384*768,
                                   gcnfb + l*64, gcnab + l*64, t2);
    int douv = (l < LL-1) ? 1 : 0;
    kcsr<<<RR/64, 256, 0, stream>>>(t2, BtCV + (size_t)l*16384, BtSR + (size_t)l*8192,
                                    filtb + l*64, gateb + l*64, skipb + l*64, resb + l*64,
                                    lng + l*64, lnb + l*64, skip, xbf, dil, l==0 ? 1 : 0, douv);
  }

  // --- tail ---
  kend2<<<RR/64, 256, 0, stream>>>(skip, BtE1, BtE2, e1b, e2b, h2);
  keeg1<<<dim3(8, SPLITK), 512, 0, stream>>>(h2, WtE, part);
  keeg2<<<BTOT, 256, 0, stream>>>(part, eg1b, eg2W, eg2b, (float*)d_out);
}